// Round 3
// baseline (8574.702 us; speedup 1.0000x reference)
//
#include <hip/hip_runtime.h>
#include <math.h>

#define B_ 64
#define T_ 100
#define S_ 32
#define L_ 128
#define R_ 16
#define H_ 256

__device__ __forceinline__ float dot4(float4 a, float4 b) {
  return a.x*b.x + a.y*b.y + a.z*b.z + a.w*b.w;
}
__device__ __forceinline__ void wave_fence() {
  asm volatile("s_waitcnt lgkmcnt(0)" ::: "memory");
  __builtin_amdgcn_wave_barrier();
}

// ---- 16x16 cholesky (row-per-lane, shfl) + explicit G = inv(L) ----
__device__ __forceinline__ void chol16_inv(int lane, float (*C2)[17], float (*G)[17], float* rd) {
  float row[16];
  #pragma unroll
  for (int c = 0; c < 16; ++c) row[c] = (lane < 16) ? C2[lane][c] : 0.0f;
  float rdg = 0.0f;
  #pragma unroll
  for (int j = 0; j < 16; ++j) {
    float dsq = __shfl(row[j], j);      // fully-updated A[j][j], broadcast
    float d = sqrtf(dsq);
    float inv = 1.0f / d;
    float cij = row[j] * inv;           // L[i][j] for i > j
    if (lane == j) { cij = d; rdg = inv; }
    row[j] = cij;
    float upd = (lane > j) ? (cij * inv) : 0.0f;  // L[i][j]/d
    #pragma unroll
    for (int c = j + 1; c < 16; ++c) {
      float cjc = __shfl(row[c], j);    // un-normalized A[j][c]
      row[c] -= upd * cjc;              // == L[i][j]*L[c][j]
    }
  }
  if (lane < 16) {
    #pragma unroll
    for (int c = 0; c < 16; ++c) C2[lane][c] = row[c];
    rd[lane] = rdg;
  }
  wave_fence();
  if (lane < 16) {            // G = inv(L): one column per lane, serial substitution
    const int c = lane;
    float g[16];
    #pragma unroll
    for (int i = 0; i < 16; ++i) {
      float a = (i == c) ? 1.0f : 0.0f;
      #pragma unroll
      for (int j2 = 0; j2 < 16; ++j2) if (j2 < i) a -= C2[i][j2] * g[j2];
      g[i] = a * rd[i];
    }
    #pragma unroll
    for (int i = 0; i < 16; ++i) G[i][c] = (i >= c) ? g[i] : 0.0f;
  }
  wave_fence();
}

// ---- 32x32 cholesky + solve (L L^T) x = t1 -> xb ----
__device__ __forceinline__ void chol32_solve(int lane, float (*C)[33], float* rd32,
                                             const float* t1, float* xb) {
  float row[32];
  #pragma unroll
  for (int c = 0; c < 32; ++c) row[c] = (lane < 32) ? C[lane][c] : 0.0f;
  float rdg = 0.0f;
  #pragma unroll
  for (int j = 0; j < 32; ++j) {
    float dsq = __shfl(row[j], j);
    float d = sqrtf(dsq);
    float inv = 1.0f / d;
    float cij = row[j] * inv;
    if (lane == j) { cij = d; rdg = inv; }
    row[j] = cij;
    float upd = (lane > j) ? (cij * inv) : 0.0f;
    #pragma unroll
    for (int c = j + 1; c < 32; ++c) {
      float cjc = __shfl(row[c], j);
      row[c] -= upd * cjc;
    }
  }
  // forward solve L y = t1 (in registers)
  float acc = (lane < 32) ? t1[lane] : 0.0f;
  #pragma unroll
  for (int j = 0; j < 32; ++j) {
    float xj = __shfl(acc, j) * __shfl(rdg, j);
    if (lane == j) acc = xj;
    else if (lane > j) acc -= row[j] * xj;
  }
  // write back L + 1/diag
  if (lane < 32) {
    #pragma unroll
    for (int c = 0; c < 32; ++c) C[lane][c] = row[c];
    rd32[lane] = rdg;
  }
  wave_fence();
  // backward solve L^T x = y via LDS publish
  float acc2 = acc;
  #pragma unroll
  for (int j = 31; j >= 0; --j) {
    if (lane == j) xb[j] = acc2 * rdg;
    wave_fence();
    float xj = xb[j];
    if (lane < j) acc2 -= C[j][lane] * xj;
  }
}

__global__ __launch_bounds__(512) void filter_kernel(
    const float* __restrict__ kg,   // (B,T,L)
    const float* __restrict__ Kg,   // (B,T,L,R)
    const float* __restrict__ m0g,  // (L)
    const float* __restrict__ Ppg,  // (L)
    const float* __restrict__ Qg,   // (L)
    const float* __restrict__ wp0,  // (S,B,L)
    const float* __restrict__ wf0,  // (S,B,R)
    const float* __restrict__ wp1s, // (T-1,S,B,S)
    const float* __restrict__ wp2s, // (T-1,S,B,L)
    const float* __restrict__ wfs,  // (T-1,S,B,R)
    const float* __restrict__ W1,   // (L,H) row-major
    const float* __restrict__ W2,   // (H,L) row-major
    float* __restrict__ out)        // (T,S,B,L)
{
  const int b = blockIdx.x;
  const int tid = threadIdx.x;

  __shared__ float zc[S_][132];     // carried z
  __shared__ float Ab[S_][264];     // tanh activations (H=256), later McQ (L=128)
  __shared__ float Mc[S_][132];     // m_theta -> Mc
  __shared__ float zp[S_][132];     // z_p_c
  __shared__ float KtT[R_][132];    // K_t transposed [r][l]
  __shared__ float w1b[S_][36];
  __shared__ float wfb[S_][20];
  __shared__ float C32m[32][33];
  __shared__ float C2m[16][17];
  __shared__ float Gm[16][17];
  __shared__ float KMm[16][36];
  __shared__ float v1b[S_][20];
  __shared__ float yb[S_][20];
  __shared__ float xv[S_][20];
  __shared__ float red[32][17];
  __shared__ float mp[L_], u1[L_], hv[L_], uu[L_], mv[L_], trp[L_], ktv[L_];
  __shared__ float Qv[L_], iQ[L_], sQ[L_], Ppv[L_], sPp[L_], m0v[L_];
  __shared__ float t1v[32], tPh[32], xbuf[32], rd32[32];
  __shared__ float ttv[16], ssv[16], rd16[16], y2v[16];

  // ---------------- init ----------------
  if (tid < L_) {
    float q = Qg[tid];  Qv[tid] = q;  iQ[tid] = 1.0f / q;  sQ[tid] = sqrtf(q);
    float p = Ppg[tid]; Ppv[tid] = p; sPp[tid] = sqrtf(p);
    m0v[tid] = m0g[tid];
  }
  __syncthreads();

  // ---------------- step 0 ----------------
  {
    { // stage K0^T
      const float* Ksrc = Kg + (size_t)b * T_ * L_ * R_;
      float4 v = *(const float4*)(Ksrc + tid * 4);
      int l = (tid * 4) >> 4, r = (tid * 4) & 15;
      KtT[r+0][l] = v.x; KtT[r+1][l] = v.y; KtT[r+2][l] = v.z; KtT[r+3][l] = v.w;
    }
    for (int e = tid; e < S_ * L_ / 4; e += 512) {   // zp0 = sqrt(Pp)*w_p0
      int s = e >> 5, l = (e & 31) * 4;
      float4 w = *(const float4*)(wp0 + ((size_t)s * B_ + b) * L_ + l);
      float4 p = *(const float4*)&sPp[l];
      *(float4*)&zp[s][l] = make_float4(w.x*p.x, w.y*p.y, w.z*p.z, w.w*p.w);
    }
    { int s = tid >> 4, r = tid & 15;
      wfb[s][r] = wf0[((size_t)s * B_ + b) * R_ + r]; }
    __syncthreads();

    // M16 = I + K0^T (Pp o K0) (sym, tid<256) || v1 (tid>=256) ; hv (tid<128)
    if (tid < 256) {
      int r1 = tid >> 4, r2 = tid & 15;
      if (r1 <= r2) {
        float acc = (r1 == r2) ? 1.0f : 0.0f;
        for (int lc = 0; lc < 32; ++lc) {
          float4 a = *(const float4*)&KtT[r1][lc*4];
          float4 c = *(const float4*)&KtT[r2][lc*4];
          float4 p = *(const float4*)&Ppv[lc*4];
          acc += a.x*c.x*p.x + a.y*c.y*p.y + a.z*c.z*p.z + a.w*c.w*p.w;
        }
        C2m[r1][r2] = acc; C2m[r2][r1] = acc;
      }
      if (tid < 128) hv[tid] = m0v[tid] / Ppv[tid] + kg[(size_t)b * T_ * L_ + tid];
    } else {
      int q2 = tid - 256, s = q2 >> 3, r = (q2 & 7) * 2;
      float a0 = wfb[s][r], a1 = wfb[s][r+1];
      for (int lc = 0; lc < 32; ++lc) {
        float4 zz = *(const float4*)&zp[s][lc*4];
        float4 ka = *(const float4*)&KtT[r][lc*4];
        float4 kb = *(const float4*)&KtT[r+1][lc*4];
        a0 += dot4(zz, ka); a1 += dot4(zz, kb);
      }
      v1b[s][r] = a0; v1b[s][r+1] = a1;
    }
    __syncthreads();
    if (tid < 64) chol16_inv(tid, C2m, Gm, rd16);
    __syncthreads();
    { // tt partials + y = G v1
      int r = tid & 15, g = tid >> 4;
      float4 a = *(const float4*)&KtT[r][g*4];
      float4 p = *(const float4*)&Ppv[g*4];
      float4 h4 = *(const float4*)&hv[g*4];
      red[g][r] = a.x*p.x*h4.x + a.y*p.y*h4.y + a.z*p.z*h4.z + a.w*p.w*h4.w;
    }
    { int s = tid >> 4, r = tid & 15;
      float a = 0;
      #pragma unroll
      for (int j = 0; j < 16; ++j) a += Gm[r][j] * v1b[s][j];
      yb[s][r] = a; }
    __syncthreads();
    { // x = G^T y  (all) ; ss (wave0)
      int s = tid >> 4, r = tid & 15;
      float a = 0;
      #pragma unroll
      for (int j = 0; j < 16; ++j) a += Gm[j][r] * yb[s][j];
      xv[s][r] = a; }
    if (tid < 64) {
      if (tid < 16) { float a = 0;
        #pragma unroll
        for (int g = 0; g < 32; ++g) a += red[g][tid];
        ttv[tid] = a; }
      wave_fence();
      if (tid < 16) { float a = 0;
        #pragma unroll
        for (int j = 0; j < 16; ++j) a += Gm[tid][j] * ttv[j];
        y2v[tid] = a; }
      wave_fence();
      if (tid < 16) { float a = 0;
        #pragma unroll
        for (int j = 0; j < 16; ++j) a += Gm[j][tid] * y2v[j];
        ssv[tid] = a; }
    }
    __syncthreads();
    if (tid < 128) {   // m = Pp*(h - K0 ss)
      float a = hv[tid];
      #pragma unroll
      for (int r = 0; r < 16; ++r) a -= KtT[r][tid] * ssv[r];
      mv[tid] = Ppv[tid] * a;
    }
    __syncthreads();
    { // z0 = m + zp - K0 x ; store + carry
      int s = tid >> 4, l0 = (tid & 15) * 8;
      float acc[8] = {0,0,0,0,0,0,0,0};
      #pragma unroll
      for (int r = 0; r < 16; ++r) {
        float xr = xv[s][r];
        float4 k1 = *(const float4*)&KtT[r][l0];
        float4 k2 = *(const float4*)&KtT[r][l0+4];
        acc[0] += k1.x*xr; acc[1] += k1.y*xr; acc[2] += k1.z*xr; acc[3] += k1.w*xr;
        acc[4] += k2.x*xr; acc[5] += k2.y*xr; acc[6] += k2.z*xr; acc[7] += k2.w*xr;
      }
      float4 o1, o2;
      o1.x = mv[l0+0] + zp[s][l0+0] - acc[0]; o1.y = mv[l0+1] + zp[s][l0+1] - acc[1];
      o1.z = mv[l0+2] + zp[s][l0+2] - acc[2]; o1.w = mv[l0+3] + zp[s][l0+3] - acc[3];
      o2.x = mv[l0+4] + zp[s][l0+4] - acc[4]; o2.y = mv[l0+5] + zp[s][l0+5] - acc[5];
      o2.z = mv[l0+6] + zp[s][l0+6] - acc[6]; o2.w = mv[l0+7] + zp[s][l0+7] - acc[7];
      *(float4*)&zc[s][l0] = o1; *(float4*)&zc[s][l0+4] = o2;
      float* orow = out + ((size_t)s * B_ + b) * L_ + l0;
      *(float4*)orow = o1; *(float4*)(orow + 4) = o2;
    }
    __syncthreads();
  }

  // ---------------- main loop ----------------
  for (int t = 1; t < T_; ++t) {
    { // stage K_t^T
      const float* Ksrc = Kg + ((size_t)b * T_ + t) * L_ * R_;
      float4 v = *(const float4*)(Ksrc + tid * 4);
      int l = (tid * 4) >> 4, r = (tid * 4) & 15;
      KtT[r+0][l] = v.x; KtT[r+1][l] = v.y; KtT[r+2][l] = v.z; KtT[r+3][l] = v.w;
    }
    if (tid < 128) ktv[tid] = kg[((size_t)b * T_ + t) * L_ + tid];
    { int s = tid >> 4, r = tid & 15;
      wfb[s][r] = wfs[(((size_t)(t-1) * S_ + s) * B_ + b) * R_ + r]; }
    { int e = tid * 2, s = e >> 5, j = e & 31;
      float2 v = *(const float2*)(wp1s + (((size_t)(t-1) * S_ + s) * B_ + b) * S_ + j);
      w1b[s][j] = v.x; w1b[s][j+1] = v.y; }

    { // GEMM1: A = tanh(z @ W1) ; W1 is (L,H) row-major -> direct
      int s = tid & 31, h0 = (tid >> 5) * 16;
      float acc[16] = {0,0,0,0,0,0,0,0,0,0,0,0,0,0,0,0};
      for (int lc = 0; lc < 32; ++lc) {
        float4 z4 = *(const float4*)&zc[s][lc*4];
        float zv[4] = {z4.x, z4.y, z4.z, z4.w};
        #pragma unroll
        for (int q = 0; q < 4; ++q) {
          const float* wrow = W1 + (lc*4 + q) * H_ + h0;
          float4 wa = *(const float4*)(wrow);
          float4 wb = *(const float4*)(wrow + 4);
          float4 wc = *(const float4*)(wrow + 8);
          float4 wd = *(const float4*)(wrow + 12);
          float zq = zv[q];
          acc[0]  += zq*wa.x; acc[1]  += zq*wa.y; acc[2]  += zq*wa.z; acc[3]  += zq*wa.w;
          acc[4]  += zq*wb.x; acc[5]  += zq*wb.y; acc[6]  += zq*wb.z; acc[7]  += zq*wb.w;
          acc[8]  += zq*wc.x; acc[9]  += zq*wc.y; acc[10] += zq*wc.z; acc[11] += zq*wc.w;
          acc[12] += zq*wd.x; acc[13] += zq*wd.y; acc[14] += zq*wd.z; acc[15] += zq*wd.w;
        }
      }
      #pragma unroll
      for (int j = 0; j < 16; ++j) Ab[s][h0 + j] = tanhf(acc[j]);
    }
    __syncthreads();
    { // GEMM2: mth = z + A @ W2 ; W2 is (H,L) row-major -> direct
      int s = tid & 31, l0 = (tid >> 5) * 8;
      float acc[8] = {0,0,0,0,0,0,0,0};
      for (int hc = 0; hc < 64; ++hc) {
        float4 a4 = *(const float4*)&Ab[s][hc*4];
        float av[4] = {a4.x, a4.y, a4.z, a4.w};
        #pragma unroll
        for (int q = 0; q < 4; ++q) {
          const float* wrow = W2 + (hc*4 + q) * L_ + l0;
          float4 wa = *(const float4*)(wrow);
          float4 wb = *(const float4*)(wrow + 4);
          float aq = av[q];
          acc[0] += aq*wa.x; acc[1] += aq*wa.y; acc[2] += aq*wa.z; acc[3] += aq*wa.w;
          acc[4] += aq*wb.x; acc[5] += aq*wb.y; acc[6] += aq*wb.z; acc[7] += aq*wb.w;
        }
      }
      #pragma unroll
      for (int j = 0; j < 8; ++j) Mc[s][l0 + j] = zc[s][l0 + j] + acc[j];
    }
    __syncthreads();
    if (tid < 128) { // mean over particles, u1 = mp/Q
      float m = 0;
      #pragma unroll 8
      for (int s = 0; s < 32; ++s) m += Mc[s][tid];
      m *= (1.0f / 32.0f);
      mp[tid] = m; u1[tid] = m * iQ[tid];
    }
    __syncthreads();
    for (int e = tid; e < S_ * L_; e += 512) {  // Mc centered, McQ (in Ab)
      int s = e >> 7, l = e & 127;
      float v = (Mc[s][l] - mp[l]) * 0.17677669529663687f;
      Mc[s][l] = v; Ab[s][l] = v * iQ[l];
    }
    __syncthreads();
    // P5: C32 (sym) ; K_M ; t1 partials ; z_p_c
    for (int e = tid; e < 1024; e += 512) {
      int s1 = e >> 5, s2 = e & 31;
      if (s1 <= s2) {
        float acc = (s1 == s2) ? 1.0f : 0.0f;
        for (int lc = 0; lc < 32; ++lc) {
          float4 a = *(const float4*)&Ab[s1][lc*4];
          float4 c = *(const float4*)&Mc[s2][lc*4];
          acc += dot4(a, c);
        }
        C32m[s1][s2] = acc; C32m[s2][s1] = acc;
      }
    }
    { int s = tid >> 4, r = tid & 15;   // K_M[r][s]
      float acc = 0;
      for (int lc = 0; lc < 32; ++lc) {
        float4 kk = *(const float4*)&KtT[r][lc*4];
        float4 mm = *(const float4*)&Mc[s][lc*4];
        acc += dot4(kk, mm);
      }
      KMm[r][s] = acc; }
    { int s = tid >> 4, g = tid & 15, l0 = g * 8;  // t1 partials
      float4 m1 = *(const float4*)&Mc[s][l0];
      float4 m2 = *(const float4*)&Mc[s][l0+4];
      float4 a1 = *(const float4*)&u1[l0];
      float4 a2 = *(const float4*)&u1[l0+4];
      red[s][g] = dot4(m1, a1) + dot4(m2, a2); }
    { int s = tid >> 4, l0 = (tid & 15) * 8;       // z_p_c
      float acc[8] = {0,0,0,0,0,0,0,0};
      for (int j = 0; j < 32; ++j) {
        float wj = w1b[s][j];
        float4 m1 = *(const float4*)&Mc[j][l0];
        float4 m2 = *(const float4*)&Mc[j][l0+4];
        acc[0] += m1.x*wj; acc[1] += m1.y*wj; acc[2] += m1.z*wj; acc[3] += m1.w*wj;
        acc[4] += m2.x*wj; acc[5] += m2.y*wj; acc[6] += m2.z*wj; acc[7] += m2.w*wj;
      }
      const float* w2src = wp2s + (((size_t)(t-1) * S_ + s) * B_ + b) * L_ + l0;
      float4 wa = *(const float4*)(w2src);
      float4 wb2 = *(const float4*)(w2src + 4);
      float4 q1 = *(const float4*)&sQ[l0];
      float4 q2 = *(const float4*)&sQ[l0+4];
      *(float4*)&zp[s][l0]   = make_float4(acc[0]+q1.x*wa.x,  acc[1]+q1.y*wa.y,
                                           acc[2]+q1.z*wa.z,  acc[3]+q1.w*wa.w);
      *(float4*)&zp[s][l0+4] = make_float4(acc[4]+q2.x*wb2.x, acc[5]+q2.y*wb2.y,
                                           acc[6]+q2.z*wb2.z, acc[7]+q2.w*wb2.w); }
    __syncthreads();
    // P6: KPK (sym, tid<256) + t1 reduce ; v1 (tid>=256)
    if (tid < 256) {
      int r1 = tid >> 4, r2 = tid & 15;
      if (r1 <= r2) {
        float acc = (r1 == r2) ? 1.0f : 0.0f;
        #pragma unroll
        for (int sc2 = 0; sc2 < 8; ++sc2) {
          float4 a = *(const float4*)&KMm[r1][sc2*4];
          float4 c = *(const float4*)&KMm[r2][sc2*4];
          acc += dot4(a, c);
        }
        for (int lc = 0; lc < 32; ++lc) {
          float4 a = *(const float4*)&KtT[r1][lc*4];
          float4 c = *(const float4*)&KtT[r2][lc*4];
          float4 q = *(const float4*)&Qv[lc*4];
          acc += a.x*c.x*q.x + a.y*c.y*q.y + a.z*c.z*q.z + a.w*c.w*q.w;
        }
        C2m[r1][r2] = acc; C2m[r2][r1] = acc;
      }
      if (tid < 32) { float a = 0;
        #pragma unroll
        for (int g = 0; g < 16; ++g) a += red[tid][g];
        t1v[tid] = a; }
    } else {
      int q2 = tid - 256, s = q2 >> 3, r = (q2 & 7) * 2;
      float a0 = wfb[s][r], a1 = wfb[s][r+1];
      for (int lc = 0; lc < 32; ++lc) {
        float4 zz = *(const float4*)&zp[s][lc*4];
        float4 ka = *(const float4*)&KtT[r][lc*4];
        float4 kb = *(const float4*)&KtT[r+1][lc*4];
        a0 += dot4(zz, ka); a1 += dot4(zz, kb);
      }
      v1b[s][r] = a0; v1b[s][r+1] = a1;
    }
    __syncthreads();
    // P7: wave0 chol32+solve ; wave1 chol16+inv
    if (tid < 64) chol32_solve(tid, C32m, rd32, t1v, xbuf);
    else if (tid < 128) chol16_inv(tid - 64, C2m, Gm, rd16);
    __syncthreads();
    // P8: y = G v1 (all) ; h = u1 - McQ^T t2 + k_t (tid<128)
    { int s = tid >> 4, r = tid & 15;
      float a = 0;
      #pragma unroll
      for (int j = 0; j < 16; ++j) a += Gm[r][j] * v1b[s][j];
      yb[s][r] = a; }
    if (tid < 128) {
      float a = u1[tid];
      #pragma unroll 8
      for (int s = 0; s < 32; ++s) a -= Ab[s][tid] * xbuf[s];
      hv[tid] = a + ktv[tid];
    }
    __syncthreads();
    // P9: x = G^T y (all) ; tPh partials
    { int s = tid >> 4, r = tid & 15;
      float a = 0;
      #pragma unroll
      for (int j = 0; j < 16; ++j) a += Gm[j][r] * yb[s][j];
      xv[s][r] = a; }
    { int s = tid >> 4, g = tid & 15, l0 = g * 8;
      float4 m1 = *(const float4*)&Mc[s][l0];
      float4 m2 = *(const float4*)&Mc[s][l0+4];
      float4 h1 = *(const float4*)&hv[l0];
      float4 h2 = *(const float4*)&hv[l0+4];
      red[s][g] = dot4(m1, h1) + dot4(m2, h2); }
    __syncthreads();
    if (tid < 32) { float a = 0;
      #pragma unroll
      for (int g = 0; g < 16; ++g) a += red[tid][g];
      tPh[tid] = a; }
    __syncthreads();
    if (tid < 128) {  // uu = P_p(h)
      float a = Qv[tid] * hv[tid];
      #pragma unroll 8
      for (int s = 0; s < 32; ++s) a += Mc[s][tid] * tPh[s];
      uu[tid] = a;
    }
    __syncthreads();
    { int r = tid & 15, g = tid >> 4;  // tt partials
      float4 a = *(const float4*)&KtT[r][g*4];
      float4 u4 = *(const float4*)&uu[g*4];
      red[g][r] = dot4(a, u4); }
    __syncthreads();
    if (tid < 64) {  // tt reduce ; ss = G^T G tt
      if (tid < 16) { float a = 0;
        #pragma unroll
        for (int g = 0; g < 32; ++g) a += red[g][tid];
        ttv[tid] = a; }
      wave_fence();
      if (tid < 16) { float a = 0;
        #pragma unroll
        for (int j = 0; j < 16; ++j) a += Gm[tid][j] * ttv[j];
        y2v[tid] = a; }
      wave_fence();
      if (tid < 16) { float a = 0;
        #pragma unroll
        for (int j = 0; j < 16; ++j) a += Gm[j][tid] * y2v[j];
        ssv[tid] = a; }
    }
    __syncthreads();
    if (tid < 128) {  // trip = K ss
      float a = 0;
      #pragma unroll
      for (int r = 0; r < 16; ++r) a += KtT[r][tid] * ssv[r];
      trp[tid] = a;
    }
    __syncthreads();
    { int s = tid >> 4, g = tid & 15, l0 = g * 8;  // tP2 partials
      float4 m1 = *(const float4*)&Mc[s][l0];
      float4 m2 = *(const float4*)&Mc[s][l0+4];
      float4 h1 = *(const float4*)&trp[l0];
      float4 h2 = *(const float4*)&trp[l0+4];
      red[s][g] = dot4(m1, h1) + dot4(m2, h2); }
    __syncthreads();
    if (tid < 32) { float a = 0;
      #pragma unroll
      for (int g = 0; g < 16; ++g) a += red[tid][g];
      tPh[tid] = a; }
    __syncthreads();
    if (tid < 128) {  // m = uu - P_p(trip)
      float a = uu[tid] - Qv[tid] * trp[tid];
      #pragma unroll 8
      for (int s = 0; s < 32; ++s) a -= Mc[s][tid] * tPh[s];
      mv[tid] = a;
    }
    __syncthreads();
    { // P16: z = m + zp - K x ; store + carry
      int s = tid >> 4, l0 = (tid & 15) * 8;
      float acc[8] = {0,0,0,0,0,0,0,0};
      #pragma unroll
      for (int r = 0; r < 16; ++r) {
        float xr = xv[s][r];
        float4 k1 = *(const float4*)&KtT[r][l0];
        float4 k2 = *(const float4*)&KtT[r][l0+4];
        acc[0] += k1.x*xr; acc[1] += k1.y*xr; acc[2] += k1.z*xr; acc[3] += k1.w*xr;
        acc[4] += k2.x*xr; acc[5] += k2.y*xr; acc[6] += k2.z*xr; acc[7] += k2.w*xr;
      }
      float4 o1, o2;
      o1.x = mv[l0+0] + zp[s][l0+0] - acc[0]; o1.y = mv[l0+1] + zp[s][l0+1] - acc[1];
      o1.z = mv[l0+2] + zp[s][l0+2] - acc[2]; o1.w = mv[l0+3] + zp[s][l0+3] - acc[3];
      o2.x = mv[l0+4] + zp[s][l0+4] - acc[4]; o2.y = mv[l0+5] + zp[s][l0+5] - acc[5];
      o2.z = mv[l0+6] + zp[s][l0+6] - acc[6]; o2.w = mv[l0+7] + zp[s][l0+7] - acc[7];
      *(float4*)&zc[s][l0] = o1; *(float4*)&zc[s][l0+4] = o2;
      float* orow = out + (((size_t)t * S_ + s) * B_ + b) * L_ + l0;
      *(float4*)orow = o1; *(float4*)(orow + 4) = o2;
    }
    __syncthreads();
  }
}

extern "C" void kernel_launch(void* const* d_in, const int* in_sizes, int n_in,
                              void* d_out, int out_size, void* d_ws, size_t ws_size,
                              hipStream_t stream) {
  const float* kg  = (const float*)d_in[0];
  const float* Kg  = (const float*)d_in[1];
  const float* m0  = (const float*)d_in[2];
  const float* Pp  = (const float*)d_in[3];
  const float* Qd  = (const float*)d_in[4];
  const float* W1  = (const float*)d_in[5];
  const float* W2  = (const float*)d_in[6];
  const float* wp0 = (const float*)d_in[7];
  const float* wf0 = (const float*)d_in[8];
  const float* wp1 = (const float*)d_in[9];
  const float* wp2 = (const float*)d_in[10];
  const float* wfs = (const float*)d_in[11];
  float* outp = (float*)d_out;
  (void)d_ws; (void)ws_size;

  filter_kernel<<<B_, 512, 0, stream>>>(kg, Kg, m0, Pp, Qd, wp0, wf0,
                                        wp1, wp2, wfs, W1, W2, outp);
}